// Round 24
// baseline (157.546 us; speedup 1.0000x reference)
//
#include <hip/hip_runtime.h>
#include <hip/hip_fp16.h>
#include <math.h>

#define N_ATOMS 100000
#define N_EDGES 1600000
#define NSTRUCT 64
#define APB 64         // atoms per bucket (= one wave in the scan)
#define NBUCK 1563     // ceil(N_ATOMS/APB)
#define EPB 8192       // edges per block in scatter pass
#define BCAP 1536      // fixed bucket capacity (mean 1024, std ~32 -> +16 sigma)
#define PLANE 800000   // N_ATOMS * 8 floats per segbuf plane

__device__ __forceinline__ float frcp(float x) { return __builtin_amdgcn_rcpf(x); }
__device__ __forceinline__ float silu(float v) { return v * frcp(1.f + __expf(-v)); }

__device__ __forceinline__ unsigned packh2(float a, float b) {
    _Float16 ha = (_Float16)a, hb = (_Float16)b;
    unsigned short ua, ub;
    __builtin_memcpy(&ua, &ha, 2);
    __builtin_memcpy(&ub, &hb, 2);
    return (unsigned)ua | ((unsigned)ub << 16);
}
__device__ __forceinline__ float hlo(unsigned u) {
    unsigned short v = (unsigned short)(u & 0xffffu);
    _Float16 h; __builtin_memcpy(&h, &v, 2); return (float)h;
}
__device__ __forceinline__ float hhi(unsigned u) {
    unsigned short v = (unsigned short)(u >> 16);
    _Float16 h; __builtin_memcpy(&h, &v, 2); return (float)h;
}

// ---------------- pack atoms (32B) + prep c1m/c1s + pack fp16 weights + zero cursors/out ----

__global__ void k_pack(const float* __restrict__ pos, const float* __restrict__ mmv,
                       const int* __restrict__ species, float* __restrict__ packed,
                       const float* __restrict__ embt,
                       const float* __restrict__ Wm1, const float* __restrict__ bm1,
                       const float* __restrict__ Ws1, const float* __restrict__ bs1,
                       const float* __restrict__ Ws2, const float* __restrict__ Ws3,
                       const float* __restrict__ Wm2, const float* __restrict__ Wm3,
                       float* __restrict__ c1m, float* __restrict__ c1s,
                       unsigned* __restrict__ pWs1, unsigned* __restrict__ pWs2,
                       unsigned* __restrict__ pWs3, unsigned* __restrict__ pWm1,
                       unsigned* __restrict__ pWm2, unsigned* __restrict__ pWm3,
                       int* __restrict__ bucket_cursor, float* __restrict__ out) {
    int tid = blockIdx.x * 256 + threadIdx.x;
    if (tid < N_ATOMS) {
        int a = tid;
        float mx = mmv[a * 3 + 0], my = mmv[a * 3 + 1], mz = mmv[a * 3 + 2];
        float px = pos[a * 3 + 0], py = pos[a * 3 + 1], pz = pos[a * 3 + 2];
        float mn = sqrtf(mx * mx + my * my + mz * mz + 1e-9f);
        float4* o = (float4*)packed;
        o[a * 2 + 0] = make_float4(mx, my, mz, px);
        o[a * 2 + 1] = make_float4(py, pz, mn, (float)species[a]);
    }
    if (tid < NBUCK) bucket_cursor[tid] = 0;
    if (tid >= 2048 && tid < 2048 + NSTRUCT) out[tid - 2048] = 0.f;
    if (tid < 1152) {
        int h = tid >> 7;
        int sp = (tid >> 5) & 3;
        int o = tid & 31;
        float c = bm1[h * 32 + o];
#pragma unroll
        for (int q = 0; q < 16; q++)
            c = fmaf(embt[sp * 16 + q], Wm1[(h * 24 + 8 + q) * 32 + o], c);
        c1m[tid] = c;
    } else if (tid < 1152 + 256) {
        int k = tid - 1152;
        int sp = k >> 6, o = k & 63;
        float c = bs1[o];
#pragma unroll
        for (int q = 0; q < 16; q++)
            c = fmaf(embt[sp * 16 + q], Ws1[(16 + q) * 64 + o], c);
        c1s[k] = c;
    }
    if (tid >= 4096 && tid < 4096 + 512) {
        int idx = tid - 4096;
        int k = idx >> 5, o2 = idx & 31;
        pWs1[idx] = packh2(Ws1[k * 64 + 2 * o2], Ws1[k * 64 + 2 * o2 + 1]);
    }
    if (tid >= 8192 && tid < 8192 + 2048) {
        int idx = tid - 8192;
        int k = idx >> 5, o2 = idx & 31;
        pWs2[idx] = packh2(Ws2[k * 64 + 2 * o2], Ws2[k * 64 + 2 * o2 + 1]);
    }
    if (tid >= 10240 && tid < 10240 + 32) {
        int idx = tid - 10240;
        pWs3[idx] = packh2(Ws3[2 * idx], Ws3[2 * idx + 1]);
    }
    if (tid >= 12288 && tid < 12288 + 1152) {
        int idx = tid - 12288;
        int h = idx >> 7, rem = idx & 127;
        int d = rem >> 4, o2 = rem & 15;
        pWm1[idx] = packh2(Wm1[(h * 24 + d) * 32 + 2 * o2],
                           Wm1[(h * 24 + d) * 32 + 2 * o2 + 1]);
    }
    if (tid >= 16384 && tid < 16384 + 4608) {
        int idx = tid - 16384;
        int h = idx / 512, rem = idx % 512;
        int d = rem >> 4, o2 = rem & 15;
        pWm2[idx] = packh2(Wm2[(h * 32 + d) * 32 + 2 * o2],
                           Wm2[(h * 32 + d) * 32 + 2 * o2 + 1]);
    }
    if (tid >= 22528 && tid < 22528 + 144) {
        int idx = tid - 22528;
        int h = idx >> 4, o2 = idx & 15;
        pWm3[idx] = packh2(Wm3[h * 32 + 2 * o2], Wm3[h * 32 + 2 * o2 + 1]);
    }
}

// ---------------- scatter (il<<17)|j into fixed-capacity bucket slots ----------------

__global__ __launch_bounds__(1024) void k_bscatter(const int* __restrict__ i_idx,
                                                   const int* __restrict__ j_idx,
                                                   int* __restrict__ bucket_cursor,
                                                   unsigned* __restrict__ vb) {
    __shared__ int h[NBUCK];
    __shared__ int gbase[NBUCK];
    int t = threadIdx.x;
    for (int k = t; k < NBUCK; k += 1024) h[k] = 0;
    __syncthreads();
    int base = blockIdx.x * EPB;
    for (int k = t; k < EPB; k += 1024) {
        int e = base + k;
        if (e < N_EDGES) atomicAdd(&h[i_idx[e] >> 6], 1);
    }
    __syncthreads();
    for (int k = t; k < NBUCK; k += 1024) {
        int c = h[k];
        gbase[k] = c ? atomicAdd(&bucket_cursor[k], c) : 0;
        h[k] = 0;   // reuse as local cursor
    }
    __syncthreads();
    for (int k = t; k < EPB; k += 1024) {
        int e = base + k;
        if (e < N_EDGES) {
            int i = i_idx[e];
            int b = i >> 6;
            int r = gbase[b] + atomicAdd(&h[b], 1);
            if (r < BCAP)
                vb[b * BCAP + r] = ((unsigned)(i & 63) << 17) | (unsigned)j_idx[e];
        }
    }
}

// ---------------- fused sort + edge compute + reduce: 4 lanes/atom, count-rank-sorted ----------------

__global__ __launch_bounds__(256) void k_fused(
    const int* __restrict__ bucket_cursor,
    const unsigned* __restrict__ vb,
    const float* __restrict__ packed, const float* __restrict__ cheb,
    float* __restrict__ segbuf) {
    __shared__ int ac[APB];
    __shared__ int st[APB];
    __shared__ int rs[APB];
    __shared__ int cntl[APB];
    __shared__ int perm[APB];
    __shared__ unsigned spj[BCAP];    // 6 KB
    __shared__ float4 apk[APB * 2];   // 2 KB
    int b = blockIdx.x, t = threadIdx.x;
    int nb = bucket_cursor[b];
    if (nb > BCAP) nb = BCAP;
    int estart = b * BCAP;
    int abase = b * APB;
    const float4* pk4 = (const float4*)packed;

    for (int k = t; k < APB * 2; k += 256) {
        int a = abase + (k >> 1);
        apk[k] = (a < N_ATOMS) ? pk4[a * 2 + (k & 1)] : make_float4(0.f, 0.f, 1.f, 0.f);
    }
    if (t < APB) ac[t] = 0;
    __syncthreads();
    for (int k = t; k < nb; k += 256)
        atomicAdd(&ac[vb[estart + k] >> 17], 1);
    __syncthreads();
    if (t < APB) {   // single-wave: scan + count-rank
        int c = ac[t];
        cntl[t] = c;
        int sum = c;
#pragma unroll
        for (int off = 1; off < 64; off <<= 1) {
            int v = __shfl_up(sum, off, 64);
            if (t >= off) sum += v;
        }
        st[t] = sum;
        rs[t] = sum - c;
        ac[t] = sum - c;
        int rank = 0;
        for (int k = 0; k < APB; k++) {
            int ck = cntl[k];
            rank += (ck < c) || (ck == c && k < t);
        }
        perm[rank] = t;
    }
    __syncthreads();
    for (int k = t; k < nb; k += 256) {
        unsigned v = vb[estart + k];
        int r = atomicAdd(&ac[v >> 17], 1);
        spj[r] = v & 0x1FFFFu;
    }
    __syncthreads();

    int slot = t >> 2, s = t & 3;
    int g = perm[slot];
    int a = abase + g;
    if (a >= N_ATOMS) return;

    float4 i0 = apk[g * 2 + 0], i1 = apk[g * 2 + 1];
    float mix = i0.x, miy = i0.y, miz = i0.z;
    float pix = i0.w, piy = i1.x, piz = i1.y;
    float mni = i1.z;
    int spi = (int)i1.w;
    float inv_mni = frcp(mni);
    float mhix = mix * inv_mni, mhiy = miy * inv_mni, mhiz = miz * inv_mni;
    const float* cbase = cheb + spi * 4 * 96 + s * 24;

    float sg[8][2];
    float vc[2][3];
#pragma unroll
    for (int r = 0; r < 8; r++) { sg[r][0] = 0.f; sg[r][1] = 0.f; }
#pragma unroll
    for (int n = 0; n < 2; n++) { vc[n][0] = 0.f; vc[n][1] = 0.f; vc[n][2] = 0.f; }

    auto edge = [&](float4 a0, float4 a1) {
        float mjx = a0.x, mjy = a0.y, mjz = a0.z;
        float rx = a0.w - pix, ry = a1.x - piy, rz = a1.y - piz;
        float mnj = a1.z;
        int spj_sp = (int)a1.w;

        const float4* c4 = (const float4*)(cbase + spj_sp * 96);
        float4 c00 = c4[0], c01 = c4[1], c02 = c4[2];
        float4 c10 = c4[3], c11 = c4[4], c12 = c4[5];

        float d = sqrtf(rx * rx + ry * ry + rz * rz + 1e-9f);
        float invd = frcp(d);
        float rhx = rx * invd, rhy = ry * invd, rhz = rz * invd;

        float x = fminf(fmaxf(d * (1.f / 3.f) - 1.f, -1.f), 1.f);
        float x2 = 2.f * x;
        float T0 = 1.f, T1 = x;
        float T2 = x2 * T1 - T0, T3 = x2 * T2 - T1, T4 = x2 * T3 - T2, T5 = x2 * T4 - T3;
        float T6 = x2 * T5 - T4, T7 = x2 * T6 - T5, T8 = x2 * T7 - T6, T9 = x2 * T8 - T7;
        float T10 = x2 * T9 - T8, T11 = x2 * T10 - T9;
        float fcut = (d < 6.f) ? 0.5f * (__cosf(d * 0.52359877559829887f) + 1.f) : 0.f;

        float p0 = c00.x * T0 + c00.y * T1 + c00.z * T2 + c00.w * T3
                 + c01.x * T4 + c01.y * T5 + c01.z * T6 + c01.w * T7
                 + c02.x * T8 + c02.y * T9 + c02.z * T10 + c02.w * T11;
        float p1 = c10.x * T0 + c10.y * T1 + c10.z * T2 + c10.w * T3
                 + c11.x * T4 + c11.y * T5 + c11.z * T6 + c11.w * T7
                 + c12.x * T8 + c12.y * T9 + c12.z * T10 + c12.w * T11;
        p0 *= fcut; p1 *= fcut;

        float invmnj = frcp(mnj);
        float w1 = mix * mjx + miy * mjy + miz * mjz;
        float dhi = mhix * rhx + mhiy * rhy + mhiz * rhz;
        float dhj = (mjx * rhx + mjy * rhy + mjz * rhz) * invmnj;
        float w2 = dhi * dhi, w3 = dhj * dhj;
        float cx = miy * mjz - miz * mjy;
        float cy = miz * mjx - mix * mjz;
        float cz = mix * mjy - miy * mjx;
        float w4 = rhx * cx + rhy * cy + rhz * cz;
        float w6 = w1 * inv_mni;
        float w7 = mnj * mnj;

        sg[0][0] += p0;                      sg[0][1] += p1;
        sg[1][0] = fmaf(w1, p0, sg[1][0]);   sg[1][1] = fmaf(w1, p1, sg[1][1]);
        sg[2][0] = fmaf(w2, p0, sg[2][0]);   sg[2][1] = fmaf(w2, p1, sg[2][1]);
        sg[3][0] = fmaf(w3, p0, sg[3][0]);   sg[3][1] = fmaf(w3, p1, sg[3][1]);
        sg[4][0] = fmaf(w4, p0, sg[4][0]);   sg[4][1] = fmaf(w4, p1, sg[4][1]);
        sg[5][0] = fmaf(mnj, p0, sg[5][0]);  sg[5][1] = fmaf(mnj, p1, sg[5][1]);
        sg[6][0] = fmaf(w6, p0, sg[6][0]);   sg[6][1] = fmaf(w6, p1, sg[6][1]);
        sg[7][0] = fmaf(w7, p0, sg[7][0]);   sg[7][1] = fmaf(w7, p1, sg[7][1]);
        vc[0][0] = fmaf(p0, rhx, vc[0][0]);  vc[1][0] = fmaf(p1, rhx, vc[1][0]);
        vc[0][1] = fmaf(p0, rhy, vc[0][1]);  vc[1][1] = fmaf(p1, rhy, vc[1][1]);
        vc[0][2] = fmaf(p0, rhz, vc[0][2]);  vc[1][2] = fmaf(p1, rhz, vc[1][2]);
    };

    int r0 = rs[g], r1 = st[g];
    int k = r0;
    int ja = (k < r1) ? (int)spj[k] : 0;
    int jb = (k + 1 < r1) ? (int)spj[k + 1] : 0;
    float4 x0 = pk4[ja * 2 + 0], x1 = pk4[ja * 2 + 1];
    float4 y0 = pk4[jb * 2 + 0], y1 = pk4[jb * 2 + 1];
    for (; k + 1 < r1; ) {
        int kn = k + 2;
        int jna = (kn < r1) ? (int)spj[kn] : 0;
        int jnb = (kn + 1 < r1) ? (int)spj[kn + 1] : 0;
        float4 nx0 = pk4[jna * 2 + 0], nx1 = pk4[jna * 2 + 1];
        float4 ny0 = pk4[jnb * 2 + 0], ny1 = pk4[jnb * 2 + 1];
        edge(x0, x1);
        edge(y0, y1);
        x0 = nx0; x1 = nx1; y0 = ny0; y1 = ny1;
        k = kn;
    }
    if (k < r1) edge(x0, x1);

#pragma unroll
    for (int r = 0; r < 8; r++)
        *(float2*)(segbuf + r * PLANE + a * 8 + s * 2) = make_float2(sg[r][0], sg[r][1]);
    float2 vn;
    vn.x = vc[0][0] * vc[0][0] + vc[0][1] * vc[0][1] + vc[0][2] * vc[0][2];
    vn.y = vc[1][0] * vc[1][0] + vc[1][1] * vc[1][1] + vc[1][2] * vc[1][2];
    *(float2*)(segbuf + 8 * PLANE + a * 8 + s * 2) = vn;
}

// ---------------- merged tail: grid.y<9 = mag head, grid.y==9 = struct MLP ----------------
// layer-2 chunks merged: each k/d step loads one contiguous 16-dword weight batch

__global__ __launch_bounds__(256, 1) void k_tail(
    const float* __restrict__ segbuf, const float* __restrict__ packed,
    const int* __restrict__ species, const int* __restrict__ batch,
    const float* __restrict__ c1s, const float* __restrict__ c1m,
    const float* __restrict__ shift,
    const unsigned* __restrict__ pWs1,
    const unsigned* __restrict__ pWs2, const float* __restrict__ bs2,
    const unsigned* __restrict__ pWs3, const float* __restrict__ bs3,
    const unsigned* __restrict__ pWm1,
    const unsigned* __restrict__ pWm2, const float* __restrict__ bm2,
    const unsigned* __restrict__ pWm3, const float* __restrict__ bm3,
    float* __restrict__ out) {
    __shared__ float spart[NSTRUCT];
    int t = threadIdx.x;
    if (t < NSTRUCT) spart[t] = 0.f;
    __syncthreads();

    int a = blockIdx.x * 256 + t;
    int y = blockIdx.y;
    if (a < N_ATOMS) {
        int spi = species[a];
        float e_acc;
        if (y == 9) {
            // ---- structure MLP ----
            const float4* pa = (const float4*)(segbuf + 0 * PLANE + a * 8);
            const float4* pv = (const float4*)(segbuf + 8 * PLANE + a * 8);
            float4 v0 = pa[0], v1 = pa[1];
            float4 v2 = pv[0], v3 = pv[1];
            float x[16] = {v0.x, v0.y, v0.z, v0.w, v1.x, v1.y, v1.z, v1.w,
                           v2.x, v2.y, v2.z, v2.w, v3.x, v3.y, v3.z, v3.w};

            __half2 h1h[32];
            const float* cb = c1s + spi * 64;
#pragma unroll
            for (int o2 = 0; o2 < 32; o2++)
                h1h[o2] = __floats2half2_rn(cb[2 * o2], cb[2 * o2 + 1]);
#pragma unroll
            for (int k = 0; k < 16; k++) {
                __half2 xh = __float2half2_rn(x[k]);
#pragma unroll
                for (int o2 = 0; o2 < 32; o2++)
                    h1h[o2] = __hfma2(xh, *(const __half2*)&pWs1[k * 32 + o2], h1h[o2]);
            }
#pragma unroll
            for (int o2 = 0; o2 < 32; o2++) {
                float lo = silu(__low2float(h1h[o2]));
                float hi = silu(__high2float(h1h[o2]));
                h1h[o2] = __floats2half2_rn(lo, hi);
            }

            float e = bs3[0] + shift[spi];
#pragma unroll
            for (int half = 0; half < 2; half++) {   // outputs [32*half, 32*half+32)
                __half2 h2h[16];
#pragma unroll
                for (int o2 = 0; o2 < 16; o2++)
                    h2h[o2] = __floats2half2_rn(bs2[half * 32 + 2 * o2],
                                                bs2[half * 32 + 2 * o2 + 1]);
#pragma unroll
                for (int k = 0; k < 64; k++) {
                    __half2 xh = (k & 1) ? __high2half2(h1h[k >> 1])
                                         : __low2half2(h1h[k >> 1]);
#pragma unroll
                    for (int o2 = 0; o2 < 16; o2++)
                        h2h[o2] = __hfma2(xh, *(const __half2*)&pWs2[k * 32 + half * 16 + o2], h2h[o2]);
                }
#pragma unroll
                for (int o2 = 0; o2 < 16; o2++) {
                    unsigned w = pWs3[half * 16 + o2];
                    e = fmaf(silu(__low2float(h2h[o2])), hlo(w), e);
                    e = fmaf(silu(__high2float(h2h[o2])), hhi(w), e);
                }
            }
            e_acc = e;
        } else {
            // ---- magnetic head y ----
            int h = y;
            int kk = (h <= 5) ? h : (h - 1);
            const float4* pk_ = (const float4*)(segbuf + kk * PLANE + a * 8);
            float4 s0 = pk_[0], s1 = pk_[1];
            float amp = (h == 0 || h == 5) ? packed[a * 8 + 6] : 1.f;
            float x[8] = {s0.x * amp, s0.y * amp, s0.z * amp, s0.w * amp,
                          s1.x * amp, s1.y * amp, s1.z * amp, s1.w * amp};

            __half2 hm1h[16];
            const float* cb = c1m + (h * 4 + spi) * 32;
#pragma unroll
            for (int o2 = 0; o2 < 16; o2++)
                hm1h[o2] = __floats2half2_rn(cb[2 * o2], cb[2 * o2 + 1]);
#pragma unroll
            for (int d = 0; d < 8; d++) {
                __half2 xh = __float2half2_rn(x[d]);
#pragma unroll
                for (int o2 = 0; o2 < 16; o2++)
                    hm1h[o2] = __hfma2(xh, *(const __half2*)&pWm1[(h * 8 + d) * 16 + o2], hm1h[o2]);
            }
            __half2 hb[32];
#pragma unroll
            for (int o2 = 0; o2 < 16; o2++) {
                hb[2 * o2 + 0] = __float2half2_rn(silu(__low2float(hm1h[o2])));
                hb[2 * o2 + 1] = __float2half2_rn(silu(__high2float(hm1h[o2])));
            }

            float e = bm3[h];
            {
                __half2 h2h[16];     // all 32 outputs at once -> one 16-dword batch per d
#pragma unroll
                for (int o2 = 0; o2 < 16; o2++)
                    h2h[o2] = __floats2half2_rn(bm2[h * 32 + 2 * o2],
                                                bm2[h * 32 + 2 * o2 + 1]);
#pragma unroll
                for (int d = 0; d < 32; d++) {
#pragma unroll
                    for (int o2 = 0; o2 < 16; o2++)
                        h2h[o2] = __hfma2(hb[d], *(const __half2*)&pWm2[(h * 32 + d) * 16 + o2], h2h[o2]);
                }
#pragma unroll
                for (int o2 = 0; o2 < 16; o2++) {
                    unsigned w = pWm3[h * 16 + o2];
                    e = fmaf(silu(__low2float(h2h[o2])), hlo(w), e);
                    e = fmaf(silu(__high2float(h2h[o2])), hhi(w), e);
                }
            }
            e_acc = e;
        }
        atomicAdd(&spart[batch[a]], e_acc);
    }
    __syncthreads();
    if (t < NSTRUCT) {
        float v = spart[t];
        if (v != 0.f) atomicAdd(&out[t], v);
    }
}

// ---------------- launch ----------------

extern "C" void kernel_launch(void* const* d_in, const int* in_sizes, int n_in,
                              void* d_out, int out_size, void* d_ws, size_t ws_size,
                              hipStream_t stream) {
    const float* pos   = (const float*)d_in[0];
    const float* mmv   = (const float*)d_in[1];
    const int* species = (const int*)d_in[2];
    const int* i_idx   = (const int*)d_in[3];
    const int* j_idx   = (const int*)d_in[4];
    const int* batch   = (const int*)d_in[5];
    const float* cheb  = (const float*)d_in[6];
    const float* embt  = (const float*)d_in[7];
    const float* shift = (const float*)d_in[8];
    const float* Ws1 = (const float*)d_in[9];
    const float* bs1 = (const float*)d_in[10];
    const float* Ws2 = (const float*)d_in[11];
    const float* bs2 = (const float*)d_in[12];
    const float* Ws3 = (const float*)d_in[13];
    const float* bs3 = (const float*)d_in[14];
    const float* Wm1 = (const float*)d_in[15];
    const float* bm1 = (const float*)d_in[16];
    const float* Wm2 = (const float*)d_in[17];
    const float* bm2 = (const float*)d_in[18];
    const float* Wm3 = (const float*)d_in[19];
    const float* bm3 = (const float*)d_in[20];
    float* out = (float*)d_out;

    char* ws = (char*)d_ws;
    int* bucket_cursor = (int*)(ws + 0);          // 6.3 KB (zeroed in k_pack)
    float* c1m         = (float*)(ws + 8192);     // 4.6 KB
    float* c1s         = (float*)(ws + 16384);    // 1 KB
    float* packed      = (float*)(ws + 20480);    // 3.2 MB
    float* segbuf      = (float*)(ws + 3220480);  // 28.8 MB (9 planes x 3.2 MB)
    unsigned* vb       = (unsigned*)(ws + 32020480); // 9.6 MB
    unsigned* pWs1     = (unsigned*)(ws + 41620480); // 2 KB
    unsigned* pWs2     = (unsigned*)(ws + 41622528); // 8 KB
    unsigned* pWs3     = (unsigned*)(ws + 41630720); // 128 B
    unsigned* pWm1     = (unsigned*)(ws + 41630848); // 4.6 KB
    unsigned* pWm2     = (unsigned*)(ws + 41635456); // 18.4 KB
    unsigned* pWm3     = (unsigned*)(ws + 41653888); // 576 B (end ~41.7 MB)

    const int NB_ATOM = (N_ATOMS + 255) / 256;     // 391
    const int NB_EPB  = (N_EDGES + EPB - 1) / EPB; // 196

    k_pack<<<NB_ATOM, 256, 0, stream>>>(pos, mmv, species, packed,
                                        embt, Wm1, bm1, Ws1, bs1, Ws2, Ws3, Wm2, Wm3,
                                        c1m, c1s, pWs1, pWs2, pWs3, pWm1, pWm2, pWm3,
                                        bucket_cursor, out);
    k_bscatter<<<NB_EPB, 1024, 0, stream>>>(i_idx, j_idx, bucket_cursor, vb);
    k_fused<<<NBUCK, 256, 0, stream>>>(bucket_cursor, vb, packed, cheb, segbuf);
    dim3 tailGrid(NB_ATOM, 10);
    k_tail<<<tailGrid, 256, 0, stream>>>(segbuf, packed, species, batch, c1s, c1m, shift,
                                         pWs1, pWs2, bs2, pWs3, bs3,
                                         pWm1, pWm2, bm2, pWm3, bm3, out);
}

// Round 25
// 147.696 us; speedup vs baseline: 1.0667x; 1.0667x over previous
//
#include <hip/hip_runtime.h>
#include <hip/hip_fp16.h>
#include <math.h>

#define N_ATOMS 100000
#define N_EDGES 1600000
#define NSTRUCT 64
#define APB 64         // atoms per bucket (= one wave in the scan)
#define NBUCK 1563     // ceil(N_ATOMS/APB)
#define EPB 8192       // edges per block in scatter pass
#define BCAP 1536      // fixed bucket capacity (mean 1024, std ~32 -> +16 sigma)
#define PLANE 800000   // N_ATOMS * 8 floats per segbuf plane

__device__ __forceinline__ float frcp(float x) { return __builtin_amdgcn_rcpf(x); }
__device__ __forceinline__ float silu(float v) { return v * frcp(1.f + __expf(-v)); }

__device__ __forceinline__ unsigned packh2(float a, float b) {
    _Float16 ha = (_Float16)a, hb = (_Float16)b;
    unsigned short ua, ub;
    __builtin_memcpy(&ua, &ha, 2);
    __builtin_memcpy(&ub, &hb, 2);
    return (unsigned)ua | ((unsigned)ub << 16);
}
__device__ __forceinline__ float hlo(unsigned u) {
    unsigned short v = (unsigned short)(u & 0xffffu);
    _Float16 h; __builtin_memcpy(&h, &v, 2); return (float)h;
}
__device__ __forceinline__ float hhi(unsigned u) {
    unsigned short v = (unsigned short)(u >> 16);
    _Float16 h; __builtin_memcpy(&h, &v, 2); return (float)h;
}

// ---------------- pack atoms (32B) + prep c1m/c1s + pack fp16 weights + zero cursors/out ----

__global__ void k_pack(const float* __restrict__ pos, const float* __restrict__ mmv,
                       const int* __restrict__ species, float* __restrict__ packed,
                       const float* __restrict__ embt,
                       const float* __restrict__ Wm1, const float* __restrict__ bm1,
                       const float* __restrict__ Ws1, const float* __restrict__ bs1,
                       const float* __restrict__ Ws2, const float* __restrict__ Ws3,
                       const float* __restrict__ Wm2, const float* __restrict__ Wm3,
                       float* __restrict__ c1m, float* __restrict__ c1s,
                       unsigned* __restrict__ pWs1, unsigned* __restrict__ pWs2,
                       unsigned* __restrict__ pWs3, unsigned* __restrict__ pWm1,
                       unsigned* __restrict__ pWm2, unsigned* __restrict__ pWm3,
                       int* __restrict__ bucket_cursor, float* __restrict__ out) {
    int tid = blockIdx.x * 256 + threadIdx.x;
    if (tid < N_ATOMS) {
        int a = tid;
        float mx = mmv[a * 3 + 0], my = mmv[a * 3 + 1], mz = mmv[a * 3 + 2];
        float px = pos[a * 3 + 0], py = pos[a * 3 + 1], pz = pos[a * 3 + 2];
        float mn = sqrtf(mx * mx + my * my + mz * mz + 1e-9f);
        float4* o = (float4*)packed;
        o[a * 2 + 0] = make_float4(mx, my, mz, px);
        o[a * 2 + 1] = make_float4(py, pz, mn, (float)species[a]);
    }
    if (tid < NBUCK) bucket_cursor[tid] = 0;
    if (tid >= 2048 && tid < 2048 + NSTRUCT) out[tid - 2048] = 0.f;
    if (tid < 1152) {
        int h = tid >> 7;
        int sp = (tid >> 5) & 3;
        int o = tid & 31;
        float c = bm1[h * 32 + o];
#pragma unroll
        for (int q = 0; q < 16; q++)
            c = fmaf(embt[sp * 16 + q], Wm1[(h * 24 + 8 + q) * 32 + o], c);
        c1m[tid] = c;
    } else if (tid < 1152 + 256) {
        int k = tid - 1152;
        int sp = k >> 6, o = k & 63;
        float c = bs1[o];
#pragma unroll
        for (int q = 0; q < 16; q++)
            c = fmaf(embt[sp * 16 + q], Ws1[(16 + q) * 64 + o], c);
        c1s[k] = c;
    }
    if (tid >= 4096 && tid < 4096 + 512) {
        int idx = tid - 4096;
        int k = idx >> 5, o2 = idx & 31;
        pWs1[idx] = packh2(Ws1[k * 64 + 2 * o2], Ws1[k * 64 + 2 * o2 + 1]);
    }
    if (tid >= 8192 && tid < 8192 + 2048) {
        int idx = tid - 8192;
        int k = idx >> 5, o2 = idx & 31;
        pWs2[idx] = packh2(Ws2[k * 64 + 2 * o2], Ws2[k * 64 + 2 * o2 + 1]);
    }
    if (tid >= 10240 && tid < 10240 + 32) {
        int idx = tid - 10240;
        pWs3[idx] = packh2(Ws3[2 * idx], Ws3[2 * idx + 1]);
    }
    if (tid >= 12288 && tid < 12288 + 1152) {
        int idx = tid - 12288;
        int h = idx >> 7, rem = idx & 127;
        int d = rem >> 4, o2 = rem & 15;
        pWm1[idx] = packh2(Wm1[(h * 24 + d) * 32 + 2 * o2],
                           Wm1[(h * 24 + d) * 32 + 2 * o2 + 1]);
    }
    if (tid >= 16384 && tid < 16384 + 4608) {
        int idx = tid - 16384;
        int h = idx / 512, rem = idx % 512;
        int d = rem >> 4, o2 = rem & 15;
        pWm2[idx] = packh2(Wm2[(h * 32 + d) * 32 + 2 * o2],
                           Wm2[(h * 32 + d) * 32 + 2 * o2 + 1]);
    }
    if (tid >= 22528 && tid < 22528 + 144) {
        int idx = tid - 22528;
        int h = idx >> 4, o2 = idx & 15;
        pWm3[idx] = packh2(Wm3[h * 32 + 2 * o2], Wm3[h * 32 + 2 * o2 + 1]);
    }
}

// ---------------- scatter (il<<17)|j into fixed-capacity bucket slots ----------------

__global__ __launch_bounds__(1024) void k_bscatter(const int* __restrict__ i_idx,
                                                   const int* __restrict__ j_idx,
                                                   int* __restrict__ bucket_cursor,
                                                   unsigned* __restrict__ vb) {
    __shared__ int h[NBUCK];
    __shared__ int gbase[NBUCK];
    int t = threadIdx.x;
    for (int k = t; k < NBUCK; k += 1024) h[k] = 0;
    __syncthreads();
    int base = blockIdx.x * EPB;
    for (int k = t; k < EPB; k += 1024) {
        int e = base + k;
        if (e < N_EDGES) atomicAdd(&h[i_idx[e] >> 6], 1);
    }
    __syncthreads();
    for (int k = t; k < NBUCK; k += 1024) {
        int c = h[k];
        gbase[k] = c ? atomicAdd(&bucket_cursor[k], c) : 0;
        h[k] = 0;   // reuse as local cursor
    }
    __syncthreads();
    for (int k = t; k < EPB; k += 1024) {
        int e = base + k;
        if (e < N_EDGES) {
            int i = i_idx[e];
            int b = i >> 6;
            int r = gbase[b] + atomicAdd(&h[b], 1);
            if (r < BCAP)
                vb[b * BCAP + r] = ((unsigned)(i & 63) << 17) | (unsigned)j_idx[e];
        }
    }
}

// ---------------- fused sort + edge compute + reduce: 4 lanes/atom, count-rank-sorted ----------------

__global__ __launch_bounds__(256) void k_fused(
    const int* __restrict__ bucket_cursor,
    const unsigned* __restrict__ vb,
    const float* __restrict__ packed, const float* __restrict__ cheb,
    float* __restrict__ segbuf) {
    __shared__ int ac[APB];
    __shared__ int st[APB];
    __shared__ int rs[APB];
    __shared__ int cntl[APB];
    __shared__ int perm[APB];
    __shared__ unsigned spj[BCAP];    // 6 KB
    __shared__ float4 apk[APB * 2];   // 2 KB
    int b = blockIdx.x, t = threadIdx.x;
    int nb = bucket_cursor[b];
    if (nb > BCAP) nb = BCAP;
    int estart = b * BCAP;
    int abase = b * APB;
    const float4* pk4 = (const float4*)packed;

    for (int k = t; k < APB * 2; k += 256) {
        int a = abase + (k >> 1);
        apk[k] = (a < N_ATOMS) ? pk4[a * 2 + (k & 1)] : make_float4(0.f, 0.f, 1.f, 0.f);
    }
    if (t < APB) ac[t] = 0;
    __syncthreads();
    for (int k = t; k < nb; k += 256)
        atomicAdd(&ac[vb[estart + k] >> 17], 1);
    __syncthreads();
    if (t < APB) {   // single-wave: scan + count-rank
        int c = ac[t];
        cntl[t] = c;
        int sum = c;
#pragma unroll
        for (int off = 1; off < 64; off <<= 1) {
            int v = __shfl_up(sum, off, 64);
            if (t >= off) sum += v;
        }
        st[t] = sum;
        rs[t] = sum - c;
        ac[t] = sum - c;
        int rank = 0;
        for (int k = 0; k < APB; k++) {
            int ck = cntl[k];
            rank += (ck < c) || (ck == c && k < t);
        }
        perm[rank] = t;
    }
    __syncthreads();
    for (int k = t; k < nb; k += 256) {
        unsigned v = vb[estart + k];
        int r = atomicAdd(&ac[v >> 17], 1);
        spj[r] = v & 0x1FFFFu;
    }
    __syncthreads();

    int slot = t >> 2, s = t & 3;
    int g = perm[slot];
    int a = abase + g;
    if (a >= N_ATOMS) return;

    float4 i0 = apk[g * 2 + 0], i1 = apk[g * 2 + 1];
    float mix = i0.x, miy = i0.y, miz = i0.z;
    float pix = i0.w, piy = i1.x, piz = i1.y;
    float mni = i1.z;
    int spi = (int)i1.w;
    float inv_mni = frcp(mni);
    float mhix = mix * inv_mni, mhiy = miy * inv_mni, mhiz = miz * inv_mni;
    const float* cbase = cheb + spi * 4 * 96 + s * 24;

    float sg[8][2];
    float vc[2][3];
#pragma unroll
    for (int r = 0; r < 8; r++) { sg[r][0] = 0.f; sg[r][1] = 0.f; }
#pragma unroll
    for (int n = 0; n < 2; n++) { vc[n][0] = 0.f; vc[n][1] = 0.f; vc[n][2] = 0.f; }

    auto edge = [&](float4 a0, float4 a1) {
        float mjx = a0.x, mjy = a0.y, mjz = a0.z;
        float rx = a0.w - pix, ry = a1.x - piy, rz = a1.y - piz;
        float mnj = a1.z;
        int spj_sp = (int)a1.w;

        const float4* c4 = (const float4*)(cbase + spj_sp * 96);
        float4 c00 = c4[0], c01 = c4[1], c02 = c4[2];
        float4 c10 = c4[3], c11 = c4[4], c12 = c4[5];

        float d = sqrtf(rx * rx + ry * ry + rz * rz + 1e-9f);
        float invd = frcp(d);
        float rhx = rx * invd, rhy = ry * invd, rhz = rz * invd;

        float x = fminf(fmaxf(d * (1.f / 3.f) - 1.f, -1.f), 1.f);
        float x2 = 2.f * x;
        float T0 = 1.f, T1 = x;
        float T2 = x2 * T1 - T0, T3 = x2 * T2 - T1, T4 = x2 * T3 - T2, T5 = x2 * T4 - T3;
        float T6 = x2 * T5 - T4, T7 = x2 * T6 - T5, T8 = x2 * T7 - T6, T9 = x2 * T8 - T7;
        float T10 = x2 * T9 - T8, T11 = x2 * T10 - T9;
        float fcut = (d < 6.f) ? 0.5f * (__cosf(d * 0.52359877559829887f) + 1.f) : 0.f;

        float p0 = c00.x * T0 + c00.y * T1 + c00.z * T2 + c00.w * T3
                 + c01.x * T4 + c01.y * T5 + c01.z * T6 + c01.w * T7
                 + c02.x * T8 + c02.y * T9 + c02.z * T10 + c02.w * T11;
        float p1 = c10.x * T0 + c10.y * T1 + c10.z * T2 + c10.w * T3
                 + c11.x * T4 + c11.y * T5 + c11.z * T6 + c11.w * T7
                 + c12.x * T8 + c12.y * T9 + c12.z * T10 + c12.w * T11;
        p0 *= fcut; p1 *= fcut;

        float invmnj = frcp(mnj);
        float w1 = mix * mjx + miy * mjy + miz * mjz;
        float dhi = mhix * rhx + mhiy * rhy + mhiz * rhz;
        float dhj = (mjx * rhx + mjy * rhy + mjz * rhz) * invmnj;
        float w2 = dhi * dhi, w3 = dhj * dhj;
        float cx = miy * mjz - miz * mjy;
        float cy = miz * mjx - mix * mjz;
        float cz = mix * mjy - miy * mjx;
        float w4 = rhx * cx + rhy * cy + rhz * cz;
        float w6 = w1 * inv_mni;
        float w7 = mnj * mnj;

        sg[0][0] += p0;                      sg[0][1] += p1;
        sg[1][0] = fmaf(w1, p0, sg[1][0]);   sg[1][1] = fmaf(w1, p1, sg[1][1]);
        sg[2][0] = fmaf(w2, p0, sg[2][0]);   sg[2][1] = fmaf(w2, p1, sg[2][1]);
        sg[3][0] = fmaf(w3, p0, sg[3][0]);   sg[3][1] = fmaf(w3, p1, sg[3][1]);
        sg[4][0] = fmaf(w4, p0, sg[4][0]);   sg[4][1] = fmaf(w4, p1, sg[4][1]);
        sg[5][0] = fmaf(mnj, p0, sg[5][0]);  sg[5][1] = fmaf(mnj, p1, sg[5][1]);
        sg[6][0] = fmaf(w6, p0, sg[6][0]);   sg[6][1] = fmaf(w6, p1, sg[6][1]);
        sg[7][0] = fmaf(w7, p0, sg[7][0]);   sg[7][1] = fmaf(w7, p1, sg[7][1]);
        vc[0][0] = fmaf(p0, rhx, vc[0][0]);  vc[1][0] = fmaf(p1, rhx, vc[1][0]);
        vc[0][1] = fmaf(p0, rhy, vc[0][1]);  vc[1][1] = fmaf(p1, rhy, vc[1][1]);
        vc[0][2] = fmaf(p0, rhz, vc[0][2]);  vc[1][2] = fmaf(p1, rhz, vc[1][2]);
    };

    int r0 = rs[g], r1 = st[g];
    int k = r0;
    int ja = (k < r1) ? (int)spj[k] : 0;
    int jb = (k + 1 < r1) ? (int)spj[k + 1] : 0;
    float4 x0 = pk4[ja * 2 + 0], x1 = pk4[ja * 2 + 1];
    float4 y0 = pk4[jb * 2 + 0], y1 = pk4[jb * 2 + 1];
    for (; k + 1 < r1; ) {
        int kn = k + 2;
        int jna = (kn < r1) ? (int)spj[kn] : 0;
        int jnb = (kn + 1 < r1) ? (int)spj[kn + 1] : 0;
        float4 nx0 = pk4[jna * 2 + 0], nx1 = pk4[jna * 2 + 1];
        float4 ny0 = pk4[jnb * 2 + 0], ny1 = pk4[jnb * 2 + 1];
        edge(x0, x1);
        edge(y0, y1);
        x0 = nx0; x1 = nx1; y0 = ny0; y1 = ny1;
        k = kn;
    }
    if (k < r1) edge(x0, x1);

#pragma unroll
    for (int r = 0; r < 8; r++)
        *(float2*)(segbuf + r * PLANE + a * 8 + s * 2) = make_float2(sg[r][0], sg[r][1]);
    float2 vn;
    vn.x = vc[0][0] * vc[0][0] + vc[0][1] * vc[0][1] + vc[0][2] * vc[0][2];
    vn.y = vc[1][0] * vc[1][0] + vc[1][1] * vc[1][1] + vc[1][2] * vc[1][2];
    *(float2*)(segbuf + 8 * PLANE + a * 8 + s * 2) = vn;
}

// ---------------- merged tail: grid.y<9 = mag head, grid.y==9 = struct MLP ----------------
// round-23 version (best measured): fp16-resident hidden state, 8-wide layer-2 chunks

__global__ __launch_bounds__(256, 1) void k_tail(
    const float* __restrict__ segbuf, const float* __restrict__ packed,
    const int* __restrict__ species, const int* __restrict__ batch,
    const float* __restrict__ c1s, const float* __restrict__ c1m,
    const float* __restrict__ shift,
    const unsigned* __restrict__ pWs1,
    const unsigned* __restrict__ pWs2, const float* __restrict__ bs2,
    const unsigned* __restrict__ pWs3, const float* __restrict__ bs3,
    const unsigned* __restrict__ pWm1,
    const unsigned* __restrict__ pWm2, const float* __restrict__ bm2,
    const unsigned* __restrict__ pWm3, const float* __restrict__ bm3,
    float* __restrict__ out) {
    __shared__ float spart[NSTRUCT];
    int t = threadIdx.x;
    if (t < NSTRUCT) spart[t] = 0.f;
    __syncthreads();

    int a = blockIdx.x * 256 + t;
    int y = blockIdx.y;
    if (a < N_ATOMS) {
        int spi = species[a];
        float e_acc;
        if (y == 9) {
            // ---- structure MLP (fp16-resident hidden state) ----
            const float4* pa = (const float4*)(segbuf + 0 * PLANE + a * 8);
            const float4* pv = (const float4*)(segbuf + 8 * PLANE + a * 8);
            float4 v0 = pa[0], v1 = pa[1];
            float4 v2 = pv[0], v3 = pv[1];
            float x[16] = {v0.x, v0.y, v0.z, v0.w, v1.x, v1.y, v1.z, v1.w,
                           v2.x, v2.y, v2.z, v2.w, v3.x, v3.y, v3.z, v3.w};

            __half2 h1h[32];
            const float* cb = c1s + spi * 64;
#pragma unroll
            for (int o2 = 0; o2 < 32; o2++)
                h1h[o2] = __floats2half2_rn(cb[2 * o2], cb[2 * o2 + 1]);
#pragma unroll
            for (int k = 0; k < 16; k++) {
                __half2 xh = __float2half2_rn(x[k]);
#pragma unroll
                for (int o2 = 0; o2 < 32; o2++)
                    h1h[o2] = __hfma2(xh, *(const __half2*)&pWs1[k * 32 + o2], h1h[o2]);
            }
            // silu in f32, store back packed (h1 stays 32 regs)
#pragma unroll
            for (int o2 = 0; o2 < 32; o2++) {
                float lo = silu(__low2float(h1h[o2]));
                float hi = silu(__high2float(h1h[o2]));
                h1h[o2] = __floats2half2_rn(lo, hi);
            }

            float e = bs3[0] + shift[spi];
#pragma unroll
            for (int cbk = 0; cbk < 4; cbk++) {
                __half2 h2h[8];
#pragma unroll
                for (int o2 = 0; o2 < 8; o2++)
                    h2h[o2] = __floats2half2_rn(bs2[cbk * 16 + 2 * o2],
                                                bs2[cbk * 16 + 2 * o2 + 1]);
#pragma unroll
                for (int k = 0; k < 64; k++) {
                    __half2 xh = (k & 1) ? __high2half2(h1h[k >> 1])
                                         : __low2half2(h1h[k >> 1]);
#pragma unroll
                    for (int o2 = 0; o2 < 8; o2++)
                        h2h[o2] = __hfma2(xh, *(const __half2*)&pWs2[k * 32 + cbk * 8 + o2], h2h[o2]);
                }
#pragma unroll
                for (int o2 = 0; o2 < 8; o2++) {
                    unsigned w = pWs3[cbk * 8 + o2];
                    e = fmaf(silu(__low2float(h2h[o2])), hlo(w), e);
                    e = fmaf(silu(__high2float(h2h[o2])), hhi(w), e);
                }
            }
            e_acc = e;
        } else {
            // ---- magnetic head y (fp16-resident hidden state) ----
            int h = y;
            int kk = (h <= 5) ? h : (h - 1);
            const float4* pk_ = (const float4*)(segbuf + kk * PLANE + a * 8);
            float4 s0 = pk_[0], s1 = pk_[1];
            float amp = (h == 0 || h == 5) ? packed[a * 8 + 6] : 1.f;
            float x[8] = {s0.x * amp, s0.y * amp, s0.z * amp, s0.w * amp,
                          s1.x * amp, s1.y * amp, s1.z * amp, s1.w * amp};

            __half2 hm1h[16];
            const float* cb = c1m + (h * 4 + spi) * 32;
#pragma unroll
            for (int o2 = 0; o2 < 16; o2++)
                hm1h[o2] = __floats2half2_rn(cb[2 * o2], cb[2 * o2 + 1]);
#pragma unroll
            for (int d = 0; d < 8; d++) {
                __half2 xh = __float2half2_rn(x[d]);
#pragma unroll
                for (int o2 = 0; o2 < 16; o2++)
                    hm1h[o2] = __hfma2(xh, *(const __half2*)&pWm1[(h * 8 + d) * 16 + o2], hm1h[o2]);
            }
            // silu -> broadcast half2 per element (32 regs), feeds layer2 directly
            __half2 hb[32];
#pragma unroll
            for (int o2 = 0; o2 < 16; o2++) {
                hb[2 * o2 + 0] = __float2half2_rn(silu(__low2float(hm1h[o2])));
                hb[2 * o2 + 1] = __float2half2_rn(silu(__high2float(hm1h[o2])));
            }

            float e = bm3[h];
#pragma unroll
            for (int cbk = 0; cbk < 2; cbk++) {
                __half2 h2h[8];
#pragma unroll
                for (int o2 = 0; o2 < 8; o2++)
                    h2h[o2] = __floats2half2_rn(bm2[h * 32 + cbk * 16 + 2 * o2],
                                                bm2[h * 32 + cbk * 16 + 2 * o2 + 1]);
#pragma unroll
                for (int d = 0; d < 32; d++) {
#pragma unroll
                    for (int o2 = 0; o2 < 8; o2++)
                        h2h[o2] = __hfma2(hb[d], *(const __half2*)&pWm2[(h * 32 + d) * 16 + cbk * 8 + o2], h2h[o2]);
                }
#pragma unroll
                for (int o2 = 0; o2 < 8; o2++) {
                    unsigned w = pWm3[h * 16 + cbk * 8 + o2];
                    e = fmaf(silu(__low2float(h2h[o2])), hlo(w), e);
                    e = fmaf(silu(__high2float(h2h[o2])), hhi(w), e);
                }
            }
            e_acc = e;
        }
        atomicAdd(&spart[batch[a]], e_acc);
    }
    __syncthreads();
    if (t < NSTRUCT) {
        float v = spart[t];
        if (v != 0.f) atomicAdd(&out[t], v);
    }
}

// ---------------- launch ----------------

extern "C" void kernel_launch(void* const* d_in, const int* in_sizes, int n_in,
                              void* d_out, int out_size, void* d_ws, size_t ws_size,
                              hipStream_t stream) {
    const float* pos   = (const float*)d_in[0];
    const float* mmv   = (const float*)d_in[1];
    const int* species = (const int*)d_in[2];
    const int* i_idx   = (const int*)d_in[3];
    const int* j_idx   = (const int*)d_in[4];
    const int* batch   = (const int*)d_in[5];
    const float* cheb  = (const float*)d_in[6];
    const float* embt  = (const float*)d_in[7];
    const float* shift = (const float*)d_in[8];
    const float* Ws1 = (const float*)d_in[9];
    const float* bs1 = (const float*)d_in[10];
    const float* Ws2 = (const float*)d_in[11];
    const float* bs2 = (const float*)d_in[12];
    const float* Ws3 = (const float*)d_in[13];
    const float* bs3 = (const float*)d_in[14];
    const float* Wm1 = (const float*)d_in[15];
    const float* bm1 = (const float*)d_in[16];
    const float* Wm2 = (const float*)d_in[17];
    const float* bm2 = (const float*)d_in[18];
    const float* Wm3 = (const float*)d_in[19];
    const float* bm3 = (const float*)d_in[20];
    float* out = (float*)d_out;

    char* ws = (char*)d_ws;
    int* bucket_cursor = (int*)(ws + 0);          // 6.3 KB (zeroed in k_pack)
    float* c1m         = (float*)(ws + 8192);     // 4.6 KB
    float* c1s         = (float*)(ws + 16384);    // 1 KB
    float* packed      = (float*)(ws + 20480);    // 3.2 MB
    float* segbuf      = (float*)(ws + 3220480);  // 28.8 MB (9 planes x 3.2 MB)
    unsigned* vb       = (unsigned*)(ws + 32020480); // 9.6 MB
    unsigned* pWs1     = (unsigned*)(ws + 41620480); // 2 KB
    unsigned* pWs2     = (unsigned*)(ws + 41622528); // 8 KB
    unsigned* pWs3     = (unsigned*)(ws + 41630720); // 128 B
    unsigned* pWm1     = (unsigned*)(ws + 41630848); // 4.6 KB
    unsigned* pWm2     = (unsigned*)(ws + 41635456); // 18.4 KB
    unsigned* pWm3     = (unsigned*)(ws + 41653888); // 576 B (end ~41.7 MB)

    const int NB_ATOM = (N_ATOMS + 255) / 256;     // 391
    const int NB_EPB  = (N_EDGES + EPB - 1) / EPB; // 196

    k_pack<<<NB_ATOM, 256, 0, stream>>>(pos, mmv, species, packed,
                                        embt, Wm1, bm1, Ws1, bs1, Ws2, Ws3, Wm2, Wm3,
                                        c1m, c1s, pWs1, pWs2, pWs3, pWm1, pWm2, pWm3,
                                        bucket_cursor, out);
    k_bscatter<<<NB_EPB, 1024, 0, stream>>>(i_idx, j_idx, bucket_cursor, vb);
    k_fused<<<NBUCK, 256, 0, stream>>>(bucket_cursor, vb, packed, cheb, segbuf);
    dim3 tailGrid(NB_ATOM, 10);
    k_tail<<<tailGrid, 256, 0, stream>>>(segbuf, packed, species, batch, c1s, c1m, shift,
                                         pWs1, pWs2, bs2, pWs3, bs3,
                                         pWm1, pWm2, bm2, pWm3, bm3, out);
}